// Round 19
// baseline (176.331 us; speedup 1.0000x reference)
//
#include <hip/hip_runtime.h>
#include <hip/hip_bf16.h>

// SimpleDIN v19 — v18 bf16-table main + 1-deep register prefetch of the
// next tile's A-frags (8 VGPRs, rolled loop, no arrays -> no scratch risk),
// tile-0 frags loaded pre-barrier. Prep unchanged.

typedef __attribute__((ext_vector_type(8))) short          bf16x8;
typedef __attribute__((ext_vector_type(8))) unsigned short u16x8;
typedef __attribute__((ext_vector_type(4))) float          f32x4;

#define NITEMS 100000

__device__ __forceinline__ int swz_gran(int row, int g) {
    return row * 64 + ((g ^ (row & 7)) << 3);      // u16 index of 16B granule
}
__device__ __forceinline__ int swz_elem(int row, int col) {
    return row * 64 + (((col >> 3) ^ (row & 7)) << 3) + (col & 7);
}
__device__ __forceinline__ float bits2f(unsigned int u) {
    union { unsigned int u; float f; } v; v.u = u; return v.f;
}

// ---------------- Kernel P: prep ----------------
extern "C" __global__ __launch_bounds__(256)
void din_prep(const int* __restrict__ item_ids,
              const float* __restrict__ item_table,
              const float* __restrict__ att_w1,
              const float* __restrict__ att_b1,
              __hip_bfloat16* __restrict__ gcb,
              float* __restrict__ bias_out,
              unsigned short* __restrict__ tbl16)
{
    const int t   = threadIdx.x;
    const int blk = blockIdx.x;
    if (blk >= 2068) {                            // convert: 8 f32 per thread
        const int i = (blk - 2068) * 256 + t;
        if (i < NITEMS * 8) {
            const float4* s = reinterpret_cast<const float4*>(item_table) + i * 2;
            const float4 p0 = s[0];
            const float4 p1 = s[1];
            union { u16x8 v; __hip_bfloat162 h2[4]; } cv;
            cv.h2[0] = __float22bfloat162_rn(float2{p0.x, p0.y});
            cv.h2[1] = __float22bfloat162_rn(float2{p0.z, p0.w});
            cv.h2[2] = __float22bfloat162_rn(float2{p1.x, p1.y});
            cv.h2[3] = __float22bfloat162_rn(float2{p1.z, p1.w});
            *reinterpret_cast<u16x8*>(tbl16 + (size_t)i * 8) = cv.v;
        }
        return;
    }
    if (blk >= 2048) {                            // pack: 5120 tasks
        const int i = (blk - 2048) * 256 + t;
        if (i < 64 * 80) {
            const int d = i / 80;
            const int j = i - d * 80;
            const float g = att_w1[d * 80 + j] + att_w1[(192 + d) * 80 + j];
            const float c = att_w1[(128 + d) * 80 + j];
            gcb[swz_elem(j, d)]        = __float2bfloat16(g);
            gcb[5120 + swz_elem(j, d)] = __float2bfloat16(c);
        }
        return;
    }
    if (t < 160) {                                // bias: 2 b's per block
        const int bl = t / 80;
        const int jj = t - bl * 80;
        const int b  = blk * 2 + bl;
        const int iid = item_ids[b];
        const float* tgt = item_table + (size_t)iid * 64;
        float acc = att_b1[jj];
        #pragma unroll 4
        for (int d = 0; d < 64; ++d)
            acc = fmaf(tgt[d],
                       att_w1[(64 + d) * 80 + jj] - att_w1[(192 + d) * 80 + jj],
                       acc);
        bias_out[(size_t)b * 80 + jj] = acc;
    }
}

// ---------------- shared LDS layout ----------------
struct __align__(16) LdsW {
    unsigned short gcb[10240];    // 20480 B: G | C
    float w2[80];
    float biasw[4][80];
    float wsc[4][208];
    float aux[4][128];
    float h1s[4][64];
};                                 // 28480 B

// ---------------- Kernel M (bf16 table, prefetched) ----------------
extern "C" __global__ __launch_bounds__(256, 4)
void din_main_bt(const int* __restrict__ user_ids,
                 const int* __restrict__ item_ids,
                 const int* __restrict__ seq,
                 const float* __restrict__ user_table,
                 const float* __restrict__ att_w2,
                 const float* __restrict__ pred_w1,
                 const float* __restrict__ pred_b1,
                 const float* __restrict__ pred_w2,
                 const float* __restrict__ pred_b2,
                 const float* __restrict__ pred_w3,
                 const float* __restrict__ pred_b3,
                 const unsigned short* __restrict__ gcb_g,
                 const float* __restrict__ bias_g,
                 const unsigned short* __restrict__ tbl,
                 float* __restrict__ out)
{
    __shared__ LdsW L;
    const int t  = threadIdx.x;
    const int wv = t >> 6;
    const int l  = t & 63;
    const int lr = l & 15;
    const int ks = l >> 4;
    const int b  = blockIdx.x * 4 + wv;

    {
        const u16x8* src = reinterpret_cast<const u16x8*>(gcb_g);
        u16x8* dst = reinterpret_cast<u16x8*>(L.gcb);
        #pragma unroll
        for (int i = 0; i < 5; ++i) dst[t + i * 256] = src[t + i * 256];
    }
    if (t < 80) L.w2[t] = att_w2[t];
    L.biasw[wv][l] = bias_g[(size_t)b * 80 + l];
    if (l < 16) L.biasw[wv][64 + l] = bias_g[(size_t)b * 80 + 64 + l];

    // tgt slices from bf16 table, unpacked to f32
    const int iid = item_ids[b];
    const unsigned short* tbt = tbl + (size_t)iid * 64;
    const u16x8 tA = *reinterpret_cast<const u16x8*>(tbt + 8 * ks);
    const u16x8 tB = *reinterpret_cast<const u16x8*>(tbt + 32 + 8 * ks);
    float tgl[8], tgh[8];
    #pragma unroll
    for (int e = 0; e < 8; ++e) {
        tgl[e] = bits2f((unsigned int)tA[e] << 16);
        tgh[e] = bits2f((unsigned int)tB[e] << 16);
    }
    const int uid = user_ids[b];
    const float uem = user_table[(size_t)uid * 64 + l];
    const int* seqb = seq + b * 200;

    // tile-0 A-frags loaded pre-barrier (overlaps gcb staging wait)
    const int row0 = seqb[lr];                    // srow = lr < 200 always
    u16x8 a0 = *reinterpret_cast<const u16x8*>(tbl + (size_t)row0 * 64 + 8 * ks);
    u16x8 a1 = *reinterpret_cast<const u16x8*>(tbl + (size_t)row0 * 64 + 32 + 8 * ks);
    bool  valc = true;

    __syncthreads();

    float bias_r[5], w2_r[5];
    #pragma unroll
    for (int nt = 0; nt < 5; ++nt) {
        bias_r[nt] = L.biasw[wv][nt * 16 + lr];
        w2_r[nt]   = L.w2[nt * 16 + lr];
    }

    float pl[8], ph[8];
    #pragma unroll
    for (int e = 0; e < 8; ++e) { pl[e] = 0.f; ph[e] = 0.f; }
    float mrun = -1e30f, ssum = 0.f;

    for (int mt = 0; mt < 13; ++mt) {
        // ---- prefetch next tile (issue only; waited at the rotate) ----
        u16x8 na0 = (u16x8)0, na1 = (u16x8)0;
        bool nval = false;
        if (mt < 12) {
            const int nsrow = (mt + 1) * 16 + lr;
            nval = nsrow < 200;
            const int nrow = nval ? seqb[nsrow] : 0;
            const unsigned short* nrp = tbl + (size_t)nrow * 64;
            na0 = *reinterpret_cast<const u16x8*>(nrp + 8 * ks);
            na1 = *reinterpret_cast<const u16x8*>(nrp + 32 + 8 * ks);
        }

        // ---- body (zeroing applied at consumption) ----
        u16x8 c0 = a0, c1 = a1;
        if (!valc) { c0 = (u16x8)0; c1 = (u16x8)0; }

        float b0f[8], b1f[8];
        #pragma unroll
        for (int e = 0; e < 8; ++e) {
            b0f[e] = bits2f((unsigned int)c0[e] << 16);
            b1f[e] = bits2f((unsigned int)c1[e] << 16);
        }
        union { u16x8 u; bf16x8 bf; __hip_bfloat162 h2[4]; } A2, A3;
        A2.h2[0] = __float22bfloat162_rn(float2{b0f[0] * tgl[0], b0f[1] * tgl[1]});
        A2.h2[1] = __float22bfloat162_rn(float2{b0f[2] * tgl[2], b0f[3] * tgl[3]});
        A2.h2[2] = __float22bfloat162_rn(float2{b0f[4] * tgl[4], b0f[5] * tgl[5]});
        A2.h2[3] = __float22bfloat162_rn(float2{b0f[6] * tgl[6], b0f[7] * tgl[7]});
        A3.h2[0] = __float22bfloat162_rn(float2{b1f[0] * tgh[0], b1f[1] * tgh[1]});
        A3.h2[1] = __float22bfloat162_rn(float2{b1f[2] * tgh[2], b1f[3] * tgh[3]});
        A3.h2[2] = __float22bfloat162_rn(float2{b1f[4] * tgh[4], b1f[5] * tgh[5]});
        A3.h2[3] = __float22bfloat162_rn(float2{b1f[6] * tgh[6], b1f[7] * tgh[7]});
        const bf16x8 A0 = *reinterpret_cast<const bf16x8*>(&c0);
        const bf16x8 A1 = *reinterpret_cast<const bf16x8*>(&c1);

        f32x4 acc[5];
        #pragma unroll
        for (int nt = 0; nt < 5; ++nt)
            acc[nt] = (f32x4){0.f, 0.f, 0.f, 0.f};
        #pragma unroll
        for (int nt = 0; nt < 5; ++nt) {
            const int j = nt * 16 + lr;
            const bf16x8 g0 = *reinterpret_cast<const bf16x8*>(
                &L.gcb[swz_gran(j, ks)]);
            const bf16x8 g1 = *reinterpret_cast<const bf16x8*>(
                &L.gcb[swz_gran(j, 4 + ks)]);
            const bf16x8 c0b = *reinterpret_cast<const bf16x8*>(
                &L.gcb[5120 + swz_gran(j, ks)]);
            const bf16x8 c1b = *reinterpret_cast<const bf16x8*>(
                &L.gcb[5120 + swz_gran(j, 4 + ks)]);
            acc[nt] = __builtin_amdgcn_mfma_f32_16x16x32_bf16(A0,    g0,  acc[nt], 0, 0, 0);
            acc[nt] = __builtin_amdgcn_mfma_f32_16x16x32_bf16(A1,    g1,  acc[nt], 0, 0, 0);
            acc[nt] = __builtin_amdgcn_mfma_f32_16x16x32_bf16(A2.bf, c0b, acc[nt], 0, 0, 0);
            acc[nt] = __builtin_amdgcn_mfma_f32_16x16x32_bf16(A3.bf, c1b, acc[nt], 0, 0, 0);
        }

        float pv[4];
        #pragma unroll
        for (int r = 0; r < 4; ++r) {
            const int s = mt * 16 + ks * 4 + r;
            float p = 0.f;
            #pragma unroll
            for (int nt = 0; nt < 5; ++nt)
                p += fmaxf(acc[nt][r] + bias_r[nt], 0.f) * w2_r[nt];
            p += __shfl_xor(p, 1);
            p += __shfl_xor(p, 2);
            p += __shfl_xor(p, 4);
            p += __shfl_xor(p, 8);
            if (s >= 200) p = -1e30f;
            pv[r] = p;
            if (lr == 0 && s < 200) L.wsc[wv][s] = p;
        }
        float tmax = fmaxf(fmaxf(pv[0], pv[1]), fmaxf(pv[2], pv[3]));
        tmax = fmaxf(tmax, __shfl_xor(tmax, 16));
        tmax = fmaxf(tmax, __shfl_xor(tmax, 32));
        if (tmax > mrun) {
            const float sc = __expf(mrun - tmax);
            #pragma unroll
            for (int e = 0; e < 8; ++e) { pl[e] *= sc; ph[e] *= sc; }
            ssum *= sc;
            mrun = tmax;
        }
        float w = 0.f;
        const int srow = mt * 16 + lr;
        if (valc) w = __expf(L.wsc[wv][srow] - mrun);
        ssum += w;
        #pragma unroll
        for (int e = 0; e < 8; ++e) {
            pl[e] = fmaf(w, b0f[e], pl[e]);
            ph[e] = fmaf(w, b1f[e], ph[e]);
        }

        // rotate prefetch buffers
        a0 = na0; a1 = na1; valc = nval;
    }

    #pragma unroll
    for (int msk = 1; msk < 16; msk <<= 1) {
        #pragma unroll
        for (int e = 0; e < 8; ++e) {
            pl[e] += __shfl_xor(pl[e], msk);
            ph[e] += __shfl_xor(ph[e], msk);
        }
        ssum += __shfl_xor(ssum, msk);
    }
    const float inv = 1.f / ssum;
    if (lr == 0) {
        #pragma unroll
        for (int e = 0; e < 8; ++e) {
            L.aux[wv][64 + 8 * ks + e]      = pl[e] * inv;
            L.aux[wv][64 + 32 + 8 * ks + e] = ph[e] * inv;
        }
    }
    L.aux[wv][l] = uem;

    float a0r = pred_b1[l], a1r = 0.f, a2r = 0.f, a3r = 0.f;
    #pragma unroll 4
    for (int k = 0; k < 128; k += 4) {
        a0r = fmaf(L.aux[wv][k],     pred_w1[k * 64 + l],       a0r);
        a1r = fmaf(L.aux[wv][k + 1], pred_w1[(k + 1) * 64 + l], a1r);
        a2r = fmaf(L.aux[wv][k + 2], pred_w1[(k + 2) * 64 + l], a2r);
        a3r = fmaf(L.aux[wv][k + 3], pred_w1[(k + 3) * 64 + l], a3r);
    }
    L.h1s[wv][l] = fmaxf((a0r + a1r) + (a2r + a3r), 0.f);
    const int j2 = l & 31;
    float c0r = pred_b2[j2], c1r = 0.f;
    #pragma unroll 4
    for (int k = 0; k < 64; k += 2) {
        c0r = fmaf(L.h1s[wv][k],     pred_w2[k * 32 + j2],       c0r);
        c1r = fmaf(L.h1s[wv][k + 1], pred_w2[(k + 1) * 32 + j2], c1r);
    }
    float p = fmaxf(c0r + c1r, 0.f) * pred_w3[j2];
    p += __shfl_xor(p, 1);
    p += __shfl_xor(p, 2);
    p += __shfl_xor(p, 4);
    p += __shfl_xor(p, 8);
    p += __shfl_xor(p, 16);
    if (l == 0) {
        const float z = p + pred_b3[0];
        out[b] = 1.f / (1.f + __expf(-z));
    }
}

// ---------------- Kernel M fallback (f32 table) ----------------
extern "C" __global__ __launch_bounds__(256, 4)
void din_main_f32(const int* __restrict__ user_ids,
                  const int* __restrict__ item_ids,
                  const int* __restrict__ seq,
                  const float* __restrict__ user_table,
                  const float* __restrict__ item_table,
                  const float* __restrict__ att_w2,
                  const float* __restrict__ pred_w1,
                  const float* __restrict__ pred_b1,
                  const float* __restrict__ pred_w2,
                  const float* __restrict__ pred_b2,
                  const float* __restrict__ pred_w3,
                  const float* __restrict__ pred_b3,
                  const unsigned short* __restrict__ gcb_g,
                  const float* __restrict__ bias_g,
                  float* __restrict__ out)
{
    __shared__ LdsW L;
    const int t  = threadIdx.x;
    const int wv = t >> 6;
    const int l  = t & 63;
    const int lr = l & 15;
    const int ks = l >> 4;
    const int b  = blockIdx.x * 4 + wv;

    {
        const u16x8* src = reinterpret_cast<const u16x8*>(gcb_g);
        u16x8* dst = reinterpret_cast<u16x8*>(L.gcb);
        #pragma unroll
        for (int i = 0; i < 5; ++i) dst[t + i * 256] = src[t + i * 256];
    }
    if (t < 80) L.w2[t] = att_w2[t];
    L.biasw[wv][l] = bias_g[(size_t)b * 80 + l];
    if (l < 16) L.biasw[wv][64 + l] = bias_g[(size_t)b * 80 + 64 + l];

    const int iid = item_ids[b];
    const float4* tp = reinterpret_cast<const float4*>(
        item_table + (size_t)iid * 64);
    const float4 tg0 = tp[2 * ks], tg1 = tp[2 * ks + 1];
    const float4 tg2 = tp[8 + 2 * ks], tg3 = tp[8 + 2 * ks + 1];
    const int uid = user_ids[b];
    const float uem = user_table[(size_t)uid * 64 + l];
    const int* seqb = seq + b * 200;

    __syncthreads();

    float bias_r[5], w2_r[5];
    #pragma unroll
    for (int nt = 0; nt < 5; ++nt) {
        bias_r[nt] = L.biasw[wv][nt * 16 + lr];
        w2_r[nt]   = L.w2[nt * 16 + lr];
    }

    float pl[8], ph[8];
    #pragma unroll
    for (int e = 0; e < 8; ++e) { pl[e] = 0.f; ph[e] = 0.f; }
    float mrun = -1e30f, ssum = 0.f;

    for (int mt = 0; mt < 13; ++mt) {
        const int srow = mt * 16 + lr;
        const bool val = srow < 200;
        const int row = val ? seqb[srow] : 0;
        const float4* rp = reinterpret_cast<const float4*>(
            item_table + (size_t)row * 64);
        float4 q0 = rp[2 * ks], q1 = rp[2 * ks + 1];
        float4 q2 = rp[8 + 2 * ks], q3 = rp[8 + 2 * ks + 1];
        if (!val) {
            q0 = make_float4(0.f, 0.f, 0.f, 0.f);
            q1 = make_float4(0.f, 0.f, 0.f, 0.f);
            q2 = make_float4(0.f, 0.f, 0.f, 0.f);
            q3 = make_float4(0.f, 0.f, 0.f, 0.f);
        }
        union { u16x8 u; bf16x8 bf; __hip_bfloat162 h2[4]; } A0, A1, A2, A3;
        A0.h2[0] = __float22bfloat162_rn(float2{q0.x, q0.y});
        A0.h2[1] = __float22bfloat162_rn(float2{q0.z, q0.w});
        A0.h2[2] = __float22bfloat162_rn(float2{q1.x, q1.y});
        A0.h2[3] = __float22bfloat162_rn(float2{q1.z, q1.w});
        A1.h2[0] = __float22bfloat162_rn(float2{q2.x, q2.y});
        A1.h2[1] = __float22bfloat162_rn(float2{q2.z, q2.w});
        A1.h2[2] = __float22bfloat162_rn(float2{q3.x, q3.y});
        A1.h2[3] = __float22bfloat162_rn(float2{q3.z, q3.w});
        A2.h2[0] = __float22bfloat162_rn(float2{q0.x * tg0.x, q0.y * tg0.y});
        A2.h2[1] = __float22bfloat162_rn(float2{q0.z * tg0.z, q0.w * tg0.w});
        A2.h2[2] = __float22bfloat162_rn(float2{q1.x * tg1.x, q1.y * tg1.y});
        A2.h2[3] = __float22bfloat162_rn(float2{q1.z * tg1.z, q1.w * tg1.w});
        A3.h2[0] = __float22bfloat162_rn(float2{q2.x * tg2.x, q2.y * tg2.y});
        A3.h2[1] = __float22bfloat162_rn(float2{q2.z * tg2.z, q2.w * tg2.w});
        A3.h2[2] = __float22bfloat162_rn(float2{q3.x * tg3.x, q3.y * tg3.y});
        A3.h2[3] = __float22bfloat162_rn(float2{q3.z * tg3.z, q3.w * tg3.w});

        f32x4 acc[5];
        #pragma unroll
        for (int nt = 0; nt < 5; ++nt)
            acc[nt] = (f32x4){0.f, 0.f, 0.f, 0.f};
        #pragma unroll
        for (int nt = 0; nt < 5; ++nt) {
            const int j = nt * 16 + lr;
            const bf16x8 g0 = *reinterpret_cast<const bf16x8*>(
                &L.gcb[swz_gran(j, ks)]);
            const bf16x8 g1 = *reinterpret_cast<const bf16x8*>(
                &L.gcb[swz_gran(j, 4 + ks)]);
            const bf16x8 c0 = *reinterpret_cast<const bf16x8*>(
                &L.gcb[5120 + swz_gran(j, ks)]);
            const bf16x8 c1 = *reinterpret_cast<const bf16x8*>(
                &L.gcb[5120 + swz_gran(j, 4 + ks)]);
            acc[nt] = __builtin_amdgcn_mfma_f32_16x16x32_bf16(A0.bf, g0, acc[nt], 0, 0, 0);
            acc[nt] = __builtin_amdgcn_mfma_f32_16x16x32_bf16(A1.bf, g1, acc[nt], 0, 0, 0);
            acc[nt] = __builtin_amdgcn_mfma_f32_16x16x32_bf16(A2.bf, c0, acc[nt], 0, 0, 0);
            acc[nt] = __builtin_amdgcn_mfma_f32_16x16x32_bf16(A3.bf, c1, acc[nt], 0, 0, 0);
        }

        float pv[4];
        #pragma unroll
        for (int r = 0; r < 4; ++r) {
            const int s = mt * 16 + ks * 4 + r;
            float p = 0.f;
            #pragma unroll
            for (int nt = 0; nt < 5; ++nt)
                p += fmaxf(acc[nt][r] + bias_r[nt], 0.f) * w2_r[nt];
            p += __shfl_xor(p, 1);
            p += __shfl_xor(p, 2);
            p += __shfl_xor(p, 4);
            p += __shfl_xor(p, 8);
            if (s >= 200) p = -1e30f;
            pv[r] = p;
            if (lr == 0 && s < 200) L.wsc[wv][s] = p;
        }
        float tmax = fmaxf(fmaxf(pv[0], pv[1]), fmaxf(pv[2], pv[3]));
        tmax = fmaxf(tmax, __shfl_xor(tmax, 16));
        tmax = fmaxf(tmax, __shfl_xor(tmax, 32));
        if (tmax > mrun) {
            const float sc = __expf(mrun - tmax);
            #pragma unroll
            for (int e = 0; e < 8; ++e) { pl[e] *= sc; ph[e] *= sc; }
            ssum *= sc;
            mrun = tmax;
        }
        float w = 0.f;
        if (val) w = __expf(L.wsc[wv][srow] - mrun);
        ssum += w;
        pl[0] = fmaf(w, q0.x, pl[0]); pl[1] = fmaf(w, q0.y, pl[1]);
        pl[2] = fmaf(w, q0.z, pl[2]); pl[3] = fmaf(w, q0.w, pl[3]);
        pl[4] = fmaf(w, q1.x, pl[4]); pl[5] = fmaf(w, q1.y, pl[5]);
        pl[6] = fmaf(w, q1.z, pl[6]); pl[7] = fmaf(w, q1.w, pl[7]);
        ph[0] = fmaf(w, q2.x, ph[0]); ph[1] = fmaf(w, q2.y, ph[1]);
        ph[2] = fmaf(w, q2.z, ph[2]); ph[3] = fmaf(w, q2.w, ph[3]);
        ph[4] = fmaf(w, q3.x, ph[4]); ph[5] = fmaf(w, q3.y, ph[5]);
        ph[6] = fmaf(w, q3.z, ph[6]); ph[7] = fmaf(w, q3.w, ph[7]);
    }

    #pragma unroll
    for (int msk = 1; msk < 16; msk <<= 1) {
        #pragma unroll
        for (int e = 0; e < 8; ++e) {
            pl[e] += __shfl_xor(pl[e], msk);
            ph[e] += __shfl_xor(ph[e], msk);
        }
        ssum += __shfl_xor(ssum, msk);
    }
    const float inv = 1.f / ssum;
    if (lr == 0) {
        #pragma unroll
        for (int e = 0; e < 8; ++e) {
            L.aux[wv][64 + 8 * ks + e]      = pl[e] * inv;
            L.aux[wv][64 + 32 + 8 * ks + e] = ph[e] * inv;
        }
    }
    L.aux[wv][l] = uem;

    float a0 = pred_b1[l], a1 = 0.f, a2 = 0.f, a3 = 0.f;
    #pragma unroll 4
    for (int k = 0; k < 128; k += 4) {
        a0 = fmaf(L.aux[wv][k],     pred_w1[k * 64 + l],       a0);
        a1 = fmaf(L.aux[wv][k + 1], pred_w1[(k + 1) * 64 + l], a1);
        a2 = fmaf(L.aux[wv][k + 2], pred_w1[(k + 2) * 64 + l], a2);
        a3 = fmaf(L.aux[wv][k + 3], pred_w1[(k + 3) * 64 + l], a3);
    }
    L.h1s[wv][l] = fmaxf((a0 + a1) + (a2 + a3), 0.f);
    const int j2 = l & 31;
    float c0 = pred_b2[j2], c1 = 0.f;
    #pragma unroll 4
    for (int k = 0; k < 64; k += 2) {
        c0 = fmaf(L.h1s[wv][k],     pred_w2[k * 32 + j2],       c0);
        c1 = fmaf(L.h1s[wv][k + 1], pred_w2[(k + 1) * 32 + j2], c1);
    }
    float p = fmaxf(c0 + c1, 0.f) * pred_w3[j2];
    p += __shfl_xor(p, 1);
    p += __shfl_xor(p, 2);
    p += __shfl_xor(p, 4);
    p += __shfl_xor(p, 8);
    p += __shfl_xor(p, 16);
    if (l == 0) {
        const float z = p + pred_b3[0];
        out[b] = 1.f / (1.f + __expf(-z));
    }
}

extern "C" void kernel_launch(void* const* d_in, const int* in_sizes, int n_in,
                              void* d_out, int out_size, void* d_ws, size_t ws_size,
                              hipStream_t stream)
{
    const int*   user_ids   = (const int*)  d_in[0];
    const int*   item_ids   = (const int*)  d_in[1];
    const int*   seq        = (const int*)  d_in[2];
    const float* user_table = (const float*)d_in[3];
    const float* item_table = (const float*)d_in[4];
    const float* att_w1     = (const float*)d_in[5];
    const float* att_b1     = (const float*)d_in[6];
    const float* att_w2     = (const float*)d_in[7];
    // d_in[8] = att_b2: cancels in softmax, unused
    const float* pred_w1    = (const float*)d_in[9];
    const float* pred_b1    = (const float*)d_in[10];
    const float* pred_w2    = (const float*)d_in[11];
    const float* pred_b2    = (const float*)d_in[12];
    const float* pred_w3    = (const float*)d_in[13];
    const float* pred_b3    = (const float*)d_in[14];
    float* out = (float*)d_out;

    char* ws = (char*)d_ws;
    __hip_bfloat16* gcb      = (__hip_bfloat16*)ws;                 // 20480 B
    float*          bias_ws  = (float*)(ws + 20480);                // 1310720 B
    unsigned short* tbl16    = (unsigned short*)(ws + 20480 + 1310720);
    const size_t NEED = 20480 + 1310720 + (size_t)NITEMS * 64 * 2;  // ~14.1 MB

    if (ws_size >= NEED) {
        din_prep<<<5193, 256, 0, stream>>>(item_ids, item_table, att_w1,
                                           att_b1, gcb, bias_ws, tbl16);
        din_main_bt<<<1024, 256, 0, stream>>>(user_ids, item_ids, seq,
                                              user_table, att_w2,
                                              pred_w1, pred_b1, pred_w2,
                                              pred_b2, pred_w3, pred_b3,
                                              (const unsigned short*)gcb,
                                              bias_ws, tbl16, out);
    } else {
        din_prep<<<2068, 256, 0, stream>>>(item_ids, item_table, att_w1,
                                           att_b1, gcb, bias_ws, tbl16);
        din_main_f32<<<1024, 256, 0, stream>>>(user_ids, item_ids, seq,
                                               user_table, item_table, att_w2,
                                               pred_w1, pred_b1, pred_w2,
                                               pred_b2, pred_w3, pred_b3,
                                               (const unsigned short*)gcb,
                                               bias_ws, out);
    }
}

// Round 20
// 61.932 us; speedup vs baseline: 2.8472x; 2.8472x over previous
//
#include <hip/hip_runtime.h>
#include <hip/hip_bf16.h>

// SimpleDIN v20 == v18 (measured best: 62.1 µs total, main 51 µs).
// bf16 item table in workspace: halves gather volume and transactions;
// A0/A1 MFMA frags load directly. Prep = bias + G|C pack + table conversion.
// All pipelining/occupancy variants (R4,R9,R12,R17,R19) spilled or regressed;
// this is the empirical no-spill optimum of the structure.

typedef __attribute__((ext_vector_type(8))) short          bf16x8;
typedef __attribute__((ext_vector_type(8))) unsigned short u16x8;
typedef __attribute__((ext_vector_type(4))) float          f32x4;

#define NITEMS 100000

__device__ __forceinline__ int swz_gran(int row, int g) {
    return row * 64 + ((g ^ (row & 7)) << 3);      // u16 index of 16B granule
}
__device__ __forceinline__ int swz_elem(int row, int col) {
    return row * 64 + (((col >> 3) ^ (row & 7)) << 3) + (col & 7);
}
__device__ __forceinline__ float bits2f(unsigned int u) {
    union { unsigned int u; float f; } v; v.u = u; return v.f;
}

// ---------------- Kernel P: prep ----------------
// blk<2048: bias (2 b's, t<160) | 2048..2067: G|C pack | >=2068: table->bf16
extern "C" __global__ __launch_bounds__(256)
void din_prep(const int* __restrict__ item_ids,
              const float* __restrict__ item_table,
              const float* __restrict__ att_w1,
              const float* __restrict__ att_b1,
              __hip_bfloat16* __restrict__ gcb,
              float* __restrict__ bias_out,
              unsigned short* __restrict__ tbl16)
{
    const int t   = threadIdx.x;
    const int blk = blockIdx.x;
    if (blk >= 2068) {                            // convert: 8 f32 per thread
        const int i = (blk - 2068) * 256 + t;
        if (i < NITEMS * 8) {
            const float4* s = reinterpret_cast<const float4*>(item_table) + i * 2;
            const float4 p0 = s[0];
            const float4 p1 = s[1];
            union { u16x8 v; __hip_bfloat162 h2[4]; } cv;
            cv.h2[0] = __float22bfloat162_rn(float2{p0.x, p0.y});
            cv.h2[1] = __float22bfloat162_rn(float2{p0.z, p0.w});
            cv.h2[2] = __float22bfloat162_rn(float2{p1.x, p1.y});
            cv.h2[3] = __float22bfloat162_rn(float2{p1.z, p1.w});
            *reinterpret_cast<u16x8*>(tbl16 + (size_t)i * 8) = cv.v;
        }
        return;
    }
    if (blk >= 2048) {                            // pack: 5120 tasks
        const int i = (blk - 2048) * 256 + t;
        if (i < 64 * 80) {
            const int d = i / 80;
            const int j = i - d * 80;
            const float g = att_w1[d * 80 + j] + att_w1[(192 + d) * 80 + j];
            const float c = att_w1[(128 + d) * 80 + j];
            gcb[swz_elem(j, d)]        = __float2bfloat16(g);
            gcb[5120 + swz_elem(j, d)] = __float2bfloat16(c);
        }
        return;
    }
    if (t < 160) {                                // bias: 2 b's per block
        const int bl = t / 80;
        const int jj = t - bl * 80;
        const int b  = blk * 2 + bl;
        const int iid = item_ids[b];
        const float* tgt = item_table + (size_t)iid * 64;
        float acc = att_b1[jj];
        #pragma unroll 4
        for (int d = 0; d < 64; ++d)
            acc = fmaf(tgt[d],
                       att_w1[(64 + d) * 80 + jj] - att_w1[(192 + d) * 80 + jj],
                       acc);
        bias_out[(size_t)b * 80 + jj] = acc;
    }
}

// ---------------- shared LDS layout ----------------
struct __align__(16) LdsW {
    unsigned short gcb[10240];    // 20480 B: G | C
    float w2[80];
    float biasw[4][80];
    float wsc[4][208];
    float aux[4][128];
    float h1s[4][64];
};                                 // 28480 B

// ---------------- Kernel M (bf16 table path) ----------------
extern "C" __global__ __launch_bounds__(256, 4)
void din_main_bt(const int* __restrict__ user_ids,
                 const int* __restrict__ item_ids,
                 const int* __restrict__ seq,
                 const float* __restrict__ user_table,
                 const float* __restrict__ att_w2,
                 const float* __restrict__ pred_w1,
                 const float* __restrict__ pred_b1,
                 const float* __restrict__ pred_w2,
                 const float* __restrict__ pred_b2,
                 const float* __restrict__ pred_w3,
                 const float* __restrict__ pred_b3,
                 const unsigned short* __restrict__ gcb_g,
                 const float* __restrict__ bias_g,
                 const unsigned short* __restrict__ tbl,
                 float* __restrict__ out)
{
    __shared__ LdsW L;
    const int t  = threadIdx.x;
    const int wv = t >> 6;
    const int l  = t & 63;
    const int lr = l & 15;
    const int ks = l >> 4;
    const int b  = blockIdx.x * 4 + wv;

    {
        const u16x8* src = reinterpret_cast<const u16x8*>(gcb_g);
        u16x8* dst = reinterpret_cast<u16x8*>(L.gcb);
        #pragma unroll
        for (int i = 0; i < 5; ++i) dst[t + i * 256] = src[t + i * 256];
    }
    if (t < 80) L.w2[t] = att_w2[t];
    L.biasw[wv][l] = bias_g[(size_t)b * 80 + l];
    if (l < 16) L.biasw[wv][64 + l] = bias_g[(size_t)b * 80 + 64 + l];

    // tgt slices from bf16 table, unpacked to f32
    const int iid = item_ids[b];
    const unsigned short* tbt = tbl + (size_t)iid * 64;
    const u16x8 tA = *reinterpret_cast<const u16x8*>(tbt + 8 * ks);
    const u16x8 tB = *reinterpret_cast<const u16x8*>(tbt + 32 + 8 * ks);
    float tgl[8], tgh[8];
    #pragma unroll
    for (int e = 0; e < 8; ++e) {
        tgl[e] = bits2f((unsigned int)tA[e] << 16);
        tgh[e] = bits2f((unsigned int)tB[e] << 16);
    }
    const int uid = user_ids[b];
    const float uem = user_table[(size_t)uid * 64 + l];
    const int* seqb = seq + b * 200;

    __syncthreads();

    float bias_r[5], w2_r[5];
    #pragma unroll
    for (int nt = 0; nt < 5; ++nt) {
        bias_r[nt] = L.biasw[wv][nt * 16 + lr];
        w2_r[nt]   = L.w2[nt * 16 + lr];
    }

    float pl[8], ph[8];
    #pragma unroll
    for (int e = 0; e < 8; ++e) { pl[e] = 0.f; ph[e] = 0.f; }
    float mrun = -1e30f, ssum = 0.f;

    for (int mt = 0; mt < 13; ++mt) {
        const int srow = mt * 16 + lr;
        const bool val = srow < 200;
        const int row = val ? seqb[srow] : 0;
        const unsigned short* rp = tbl + (size_t)row * 64;
        u16x8 a0 = *reinterpret_cast<const u16x8*>(rp + 8 * ks);
        u16x8 a1 = *reinterpret_cast<const u16x8*>(rp + 32 + 8 * ks);
        if (!val) { a0 = (u16x8)0; a1 = (u16x8)0; }

        float b0f[8], b1f[8];
        #pragma unroll
        for (int e = 0; e < 8; ++e) {
            b0f[e] = bits2f((unsigned int)a0[e] << 16);
            b1f[e] = bits2f((unsigned int)a1[e] << 16);
        }
        union { u16x8 u; bf16x8 bf; __hip_bfloat162 h2[4]; } A2, A3;
        A2.h2[0] = __float22bfloat162_rn(float2{b0f[0] * tgl[0], b0f[1] * tgl[1]});
        A2.h2[1] = __float22bfloat162_rn(float2{b0f[2] * tgl[2], b0f[3] * tgl[3]});
        A2.h2[2] = __float22bfloat162_rn(float2{b0f[4] * tgl[4], b0f[5] * tgl[5]});
        A2.h2[3] = __float22bfloat162_rn(float2{b0f[6] * tgl[6], b0f[7] * tgl[7]});
        A3.h2[0] = __float22bfloat162_rn(float2{b1f[0] * tgh[0], b1f[1] * tgh[1]});
        A3.h2[1] = __float22bfloat162_rn(float2{b1f[2] * tgh[2], b1f[3] * tgh[3]});
        A3.h2[2] = __float22bfloat162_rn(float2{b1f[4] * tgh[4], b1f[5] * tgh[5]});
        A3.h2[3] = __float22bfloat162_rn(float2{b1f[6] * tgh[6], b1f[7] * tgh[7]});
        const bf16x8 A0 = *reinterpret_cast<const bf16x8*>(&a0);
        const bf16x8 A1 = *reinterpret_cast<const bf16x8*>(&a1);

        f32x4 acc[5];
        #pragma unroll
        for (int nt = 0; nt < 5; ++nt)
            acc[nt] = (f32x4){0.f, 0.f, 0.f, 0.f};
        #pragma unroll
        for (int nt = 0; nt < 5; ++nt) {
            const int j = nt * 16 + lr;
            const bf16x8 g0 = *reinterpret_cast<const bf16x8*>(
                &L.gcb[swz_gran(j, ks)]);
            const bf16x8 g1 = *reinterpret_cast<const bf16x8*>(
                &L.gcb[swz_gran(j, 4 + ks)]);
            const bf16x8 c0 = *reinterpret_cast<const bf16x8*>(
                &L.gcb[5120 + swz_gran(j, ks)]);
            const bf16x8 c1 = *reinterpret_cast<const bf16x8*>(
                &L.gcb[5120 + swz_gran(j, 4 + ks)]);
            acc[nt] = __builtin_amdgcn_mfma_f32_16x16x32_bf16(A0,    g0, acc[nt], 0, 0, 0);
            acc[nt] = __builtin_amdgcn_mfma_f32_16x16x32_bf16(A1,    g1, acc[nt], 0, 0, 0);
            acc[nt] = __builtin_amdgcn_mfma_f32_16x16x32_bf16(A2.bf, c0, acc[nt], 0, 0, 0);
            acc[nt] = __builtin_amdgcn_mfma_f32_16x16x32_bf16(A3.bf, c1, acc[nt], 0, 0, 0);
        }

        float pv[4];
        #pragma unroll
        for (int r = 0; r < 4; ++r) {
            const int s = mt * 16 + ks * 4 + r;
            float p = 0.f;
            #pragma unroll
            for (int nt = 0; nt < 5; ++nt)
                p += fmaxf(acc[nt][r] + bias_r[nt], 0.f) * w2_r[nt];
            p += __shfl_xor(p, 1);
            p += __shfl_xor(p, 2);
            p += __shfl_xor(p, 4);
            p += __shfl_xor(p, 8);
            if (s >= 200) p = -1e30f;
            pv[r] = p;
            if (lr == 0 && s < 200) L.wsc[wv][s] = p;
        }
        float tmax = fmaxf(fmaxf(pv[0], pv[1]), fmaxf(pv[2], pv[3]));
        tmax = fmaxf(tmax, __shfl_xor(tmax, 16));
        tmax = fmaxf(tmax, __shfl_xor(tmax, 32));
        if (tmax > mrun) {
            const float sc = __expf(mrun - tmax);
            #pragma unroll
            for (int e = 0; e < 8; ++e) { pl[e] *= sc; ph[e] *= sc; }
            ssum *= sc;
            mrun = tmax;
        }
        float w = 0.f;
        if (val) w = __expf(L.wsc[wv][srow] - mrun);
        ssum += w;
        #pragma unroll
        for (int e = 0; e < 8; ++e) {
            pl[e] = fmaf(w, b0f[e], pl[e]);
            ph[e] = fmaf(w, b1f[e], ph[e]);
        }
    }

    #pragma unroll
    for (int msk = 1; msk < 16; msk <<= 1) {
        #pragma unroll
        for (int e = 0; e < 8; ++e) {
            pl[e] += __shfl_xor(pl[e], msk);
            ph[e] += __shfl_xor(ph[e], msk);
        }
        ssum += __shfl_xor(ssum, msk);
    }
    const float inv = 1.f / ssum;
    if (lr == 0) {
        #pragma unroll
        for (int e = 0; e < 8; ++e) {
            L.aux[wv][64 + 8 * ks + e]      = pl[e] * inv;
            L.aux[wv][64 + 32 + 8 * ks + e] = ph[e] * inv;
        }
    }
    L.aux[wv][l] = uem;

    float a0r = pred_b1[l], a1r = 0.f, a2r = 0.f, a3r = 0.f;
    #pragma unroll 4
    for (int k = 0; k < 128; k += 4) {
        a0r = fmaf(L.aux[wv][k],     pred_w1[k * 64 + l],       a0r);
        a1r = fmaf(L.aux[wv][k + 1], pred_w1[(k + 1) * 64 + l], a1r);
        a2r = fmaf(L.aux[wv][k + 2], pred_w1[(k + 2) * 64 + l], a2r);
        a3r = fmaf(L.aux[wv][k + 3], pred_w1[(k + 3) * 64 + l], a3r);
    }
    L.h1s[wv][l] = fmaxf((a0r + a1r) + (a2r + a3r), 0.f);
    const int j2 = l & 31;
    float c0r = pred_b2[j2], c1r = 0.f;
    #pragma unroll 4
    for (int k = 0; k < 64; k += 2) {
        c0r = fmaf(L.h1s[wv][k],     pred_w2[k * 32 + j2],       c0r);
        c1r = fmaf(L.h1s[wv][k + 1], pred_w2[(k + 1) * 32 + j2], c1r);
    }
    float p = fmaxf(c0r + c1r, 0.f) * pred_w3[j2];
    p += __shfl_xor(p, 1);
    p += __shfl_xor(p, 2);
    p += __shfl_xor(p, 4);
    p += __shfl_xor(p, 8);
    p += __shfl_xor(p, 16);
    if (l == 0) {
        const float z = p + pred_b3[0];
        out[b] = 1.f / (1.f + __expf(-z));
    }
}

// ---------------- Kernel M fallback (f32 table; v16 verbatim) ----------------
extern "C" __global__ __launch_bounds__(256, 4)
void din_main_f32(const int* __restrict__ user_ids,
                  const int* __restrict__ item_ids,
                  const int* __restrict__ seq,
                  const float* __restrict__ user_table,
                  const float* __restrict__ item_table,
                  const float* __restrict__ att_w2,
                  const float* __restrict__ pred_w1,
                  const float* __restrict__ pred_b1,
                  const float* __restrict__ pred_w2,
                  const float* __restrict__ pred_b2,
                  const float* __restrict__ pred_w3,
                  const float* __restrict__ pred_b3,
                  const unsigned short* __restrict__ gcb_g,
                  const float* __restrict__ bias_g,
                  float* __restrict__ out)
{
    __shared__ LdsW L;
    const int t  = threadIdx.x;
    const int wv = t >> 6;
    const int l  = t & 63;
    const int lr = l & 15;
    const int ks = l >> 4;
    const int b  = blockIdx.x * 4 + wv;

    {
        const u16x8* src = reinterpret_cast<const u16x8*>(gcb_g);
        u16x8* dst = reinterpret_cast<u16x8*>(L.gcb);
        #pragma unroll
        for (int i = 0; i < 5; ++i) dst[t + i * 256] = src[t + i * 256];
    }
    if (t < 80) L.w2[t] = att_w2[t];
    L.biasw[wv][l] = bias_g[(size_t)b * 80 + l];
    if (l < 16) L.biasw[wv][64 + l] = bias_g[(size_t)b * 80 + 64 + l];

    const int iid = item_ids[b];
    const float4* tp = reinterpret_cast<const float4*>(
        item_table + (size_t)iid * 64);
    const float4 tg0 = tp[2 * ks], tg1 = tp[2 * ks + 1];
    const float4 tg2 = tp[8 + 2 * ks], tg3 = tp[8 + 2 * ks + 1];
    const int uid = user_ids[b];
    const float uem = user_table[(size_t)uid * 64 + l];
    const int* seqb = seq + b * 200;

    __syncthreads();

    float bias_r[5], w2_r[5];
    #pragma unroll
    for (int nt = 0; nt < 5; ++nt) {
        bias_r[nt] = L.biasw[wv][nt * 16 + lr];
        w2_r[nt]   = L.w2[nt * 16 + lr];
    }

    float pl[8], ph[8];
    #pragma unroll
    for (int e = 0; e < 8; ++e) { pl[e] = 0.f; ph[e] = 0.f; }
    float mrun = -1e30f, ssum = 0.f;

    for (int mt = 0; mt < 13; ++mt) {
        const int srow = mt * 16 + lr;
        const bool val = srow < 200;
        const int row = val ? seqb[srow] : 0;
        const float4* rp = reinterpret_cast<const float4*>(
            item_table + (size_t)row * 64);
        float4 q0 = rp[2 * ks], q1 = rp[2 * ks + 1];
        float4 q2 = rp[8 + 2 * ks], q3 = rp[8 + 2 * ks + 1];
        if (!val) {
            q0 = make_float4(0.f, 0.f, 0.f, 0.f);
            q1 = make_float4(0.f, 0.f, 0.f, 0.f);
            q2 = make_float4(0.f, 0.f, 0.f, 0.f);
            q3 = make_float4(0.f, 0.f, 0.f, 0.f);
        }
        union { u16x8 u; bf16x8 bf; __hip_bfloat162 h2[4]; } A0, A1, A2, A3;
        A0.h2[0] = __float22bfloat162_rn(float2{q0.x, q0.y});
        A0.h2[1] = __float22bfloat162_rn(float2{q0.z, q0.w});
        A0.h2[2] = __float22bfloat162_rn(float2{q1.x, q1.y});
        A0.h2[3] = __float22bfloat162_rn(float2{q1.z, q1.w});
        A1.h2[0] = __float22bfloat162_rn(float2{q2.x, q2.y});
        A1.h2[1] = __float22bfloat162_rn(float2{q2.z, q2.w});
        A1.h2[2] = __float22bfloat162_rn(float2{q3.x, q3.y});
        A1.h2[3] = __float22bfloat162_rn(float2{q3.z, q3.w});
        A2.h2[0] = __float22bfloat162_rn(float2{q0.x * tg0.x, q0.y * tg0.y});
        A2.h2[1] = __float22bfloat162_rn(float2{q0.z * tg0.z, q0.w * tg0.w});
        A2.h2[2] = __float22bfloat162_rn(float2{q1.x * tg1.x, q1.y * tg1.y});
        A2.h2[3] = __float22bfloat162_rn(float2{q1.z * tg1.z, q1.w * tg1.w});
        A3.h2[0] = __float22bfloat162_rn(float2{q2.x * tg2.x, q2.y * tg2.y});
        A3.h2[1] = __float22bfloat162_rn(float2{q2.z * tg2.z, q2.w * tg2.w});
        A3.h2[2] = __float22bfloat162_rn(float2{q3.x * tg3.x, q3.y * tg3.y});
        A3.h2[3] = __float22bfloat162_rn(float2{q3.z * tg3.z, q3.w * tg3.w});

        f32x4 acc[5];
        #pragma unroll
        for (int nt = 0; nt < 5; ++nt)
            acc[nt] = (f32x4){0.f, 0.f, 0.f, 0.f};
        #pragma unroll
        for (int nt = 0; nt < 5; ++nt) {
            const int j = nt * 16 + lr;
            const bf16x8 g0 = *reinterpret_cast<const bf16x8*>(
                &L.gcb[swz_gran(j, ks)]);
            const bf16x8 g1 = *reinterpret_cast<const bf16x8*>(
                &L.gcb[swz_gran(j, 4 + ks)]);
            const bf16x8 c0 = *reinterpret_cast<const bf16x8*>(
                &L.gcb[5120 + swz_gran(j, ks)]);
            const bf16x8 c1 = *reinterpret_cast<const bf16x8*>(
                &L.gcb[5120 + swz_gran(j, 4 + ks)]);
            acc[nt] = __builtin_amdgcn_mfma_f32_16x16x32_bf16(A0.bf, g0, acc[nt], 0, 0, 0);
            acc[nt] = __builtin_amdgcn_mfma_f32_16x16x32_bf16(A1.bf, g1, acc[nt], 0, 0, 0);
            acc[nt] = __builtin_amdgcn_mfma_f32_16x16x32_bf16(A2.bf, c0, acc[nt], 0, 0, 0);
            acc[nt] = __builtin_amdgcn_mfma_f32_16x16x32_bf16(A3.bf, c1, acc[nt], 0, 0, 0);
        }

        float pv[4];
        #pragma unroll
        for (int r = 0; r < 4; ++r) {
            const int s = mt * 16 + ks * 4 + r;
            float p = 0.f;
            #pragma unroll
            for (int nt = 0; nt < 5; ++nt)
                p += fmaxf(acc[nt][r] + bias_r[nt], 0.f) * w2_r[nt];
            p += __shfl_xor(p, 1);
            p += __shfl_xor(p, 2);
            p += __shfl_xor(p, 4);
            p += __shfl_xor(p, 8);
            if (s >= 200) p = -1e30f;
            pv[r] = p;
            if (lr == 0 && s < 200) L.wsc[wv][s] = p;
        }
        float tmax = fmaxf(fmaxf(pv[0], pv[1]), fmaxf(pv[2], pv[3]));
        tmax = fmaxf(tmax, __shfl_xor(tmax, 16));
        tmax = fmaxf(tmax, __shfl_xor(tmax, 32));
        if (tmax > mrun) {
            const float sc = __expf(mrun - tmax);
            #pragma unroll
            for (int e = 0; e < 8; ++e) { pl[e] *= sc; ph[e] *= sc; }
            ssum *= sc;
            mrun = tmax;
        }
        float w = 0.f;
        if (val) w = __expf(L.wsc[wv][srow] - mrun);
        ssum += w;
        pl[0] = fmaf(w, q0.x, pl[0]); pl[1] = fmaf(w, q0.y, pl[1]);
        pl[2] = fmaf(w, q0.z, pl[2]); pl[3] = fmaf(w, q0.w, pl[3]);
        pl[4] = fmaf(w, q1.x, pl[4]); pl[5] = fmaf(w, q1.y, pl[5]);
        pl[6] = fmaf(w, q1.z, pl[6]); pl[7] = fmaf(w, q1.w, pl[7]);
        ph[0] = fmaf(w, q2.x, ph[0]); ph[1] = fmaf(w, q2.y, ph[1]);
        ph[2] = fmaf(w, q2.z, ph[2]); ph[3] = fmaf(w, q2.w, ph[3]);
        ph[4] = fmaf(w, q3.x, ph[4]); ph[5] = fmaf(w, q3.y, ph[5]);
        ph[6] = fmaf(w, q3.z, ph[6]); ph[7] = fmaf(w, q3.w, ph[7]);
    }

    #pragma unroll
    for (int msk = 1; msk < 16; msk <<= 1) {
        #pragma unroll
        for (int e = 0; e < 8; ++e) {
            pl[e] += __shfl_xor(pl[e], msk);
            ph[e] += __shfl_xor(ph[e], msk);
        }
        ssum += __shfl_xor(ssum, msk);
    }
    const float inv = 1.f / ssum;
    if (lr == 0) {
        #pragma unroll
        for (int e = 0; e < 8; ++e) {
            L.aux[wv][64 + 8 * ks + e]      = pl[e] * inv;
            L.aux[wv][64 + 32 + 8 * ks + e] = ph[e] * inv;
        }
    }
    L.aux[wv][l] = uem;

    float a0 = pred_b1[l], a1 = 0.f, a2 = 0.f, a3 = 0.f;
    #pragma unroll 4
    for (int k = 0; k < 128; k += 4) {
        a0 = fmaf(L.aux[wv][k],     pred_w1[k * 64 + l],       a0);
        a1 = fmaf(L.aux[wv][k + 1], pred_w1[(k + 1) * 64 + l], a1);
        a2 = fmaf(L.aux[wv][k + 2], pred_w1[(k + 2) * 64 + l], a2);
        a3 = fmaf(L.aux[wv][k + 3], pred_w1[(k + 3) * 64 + l], a3);
    }
    L.h1s[wv][l] = fmaxf((a0 + a1) + (a2 + a3), 0.f);
    const int j2 = l & 31;
    float c0 = pred_b2[j2], c1 = 0.f;
    #pragma unroll 4
    for (int k = 0; k < 64; k += 2) {
        c0 = fmaf(L.h1s[wv][k],     pred_w2[k * 32 + j2],       c0);
        c1 = fmaf(L.h1s[wv][k + 1], pred_w2[(k + 1) * 32 + j2], c1);
    }
    float p = fmaxf(c0 + c1, 0.f) * pred_w3[j2];
    p += __shfl_xor(p, 1);
    p += __shfl_xor(p, 2);
    p += __shfl_xor(p, 4);
    p += __shfl_xor(p, 8);
    p += __shfl_xor(p, 16);
    if (l == 0) {
        const float z = p + pred_b3[0];
        out[b] = 1.f / (1.f + __expf(-z));
    }
}

extern "C" void kernel_launch(void* const* d_in, const int* in_sizes, int n_in,
                              void* d_out, int out_size, void* d_ws, size_t ws_size,
                              hipStream_t stream)
{
    const int*   user_ids   = (const int*)  d_in[0];
    const int*   item_ids   = (const int*)  d_in[1];
    const int*   seq        = (const int*)  d_in[2];
    const float* user_table = (const float*)d_in[3];
    const float* item_table = (const float*)d_in[4];
    const float* att_w1     = (const float*)d_in[5];
    const float* att_b1     = (const float*)d_in[6];
    const float* att_w2     = (const float*)d_in[7];
    // d_in[8] = att_b2: cancels in softmax, unused
    const float* pred_w1    = (const float*)d_in[9];
    const float* pred_b1    = (const float*)d_in[10];
    const float* pred_w2    = (const float*)d_in[11];
    const float* pred_b2    = (const float*)d_in[12];
    const float* pred_w3    = (const float*)d_in[13];
    const float* pred_b3    = (const float*)d_in[14];
    float* out = (float*)d_out;

    char* ws = (char*)d_ws;
    __hip_bfloat16* gcb      = (__hip_bfloat16*)ws;                 // 20480 B
    float*          bias_ws  = (float*)(ws + 20480);                // 1310720 B
    unsigned short* tbl16    = (unsigned short*)(ws + 20480 + 1310720);
    const size_t NEED = 20480 + 1310720 + (size_t)NITEMS * 64 * 2;  // ~14.1 MB

    if (ws_size >= NEED) {
        // 2048 bias + 20 pack + 3125 convert
        din_prep<<<5193, 256, 0, stream>>>(item_ids, item_table, att_w1,
                                           att_b1, gcb, bias_ws, tbl16);
        din_main_bt<<<1024, 256, 0, stream>>>(user_ids, item_ids, seq,
                                              user_table, att_w2,
                                              pred_w1, pred_b1, pred_w2,
                                              pred_b2, pred_w3, pred_b3,
                                              (const unsigned short*)gcb,
                                              bias_ws, tbl16, out);
    } else {
        din_prep<<<2068, 256, 0, stream>>>(item_ids, item_table, att_w1,
                                           att_b1, gcb, bias_ws, tbl16);
        din_main_f32<<<1024, 256, 0, stream>>>(user_ids, item_ids, seq,
                                               user_table, item_table, att_w2,
                                               pred_w1, pred_b1, pred_w2,
                                               pred_b2, pred_w3, pred_b3,
                                               (const unsigned short*)gcb,
                                               bias_ws, out);
    }
}